// Round 8
// baseline (288.634 us; speedup 1.0000x reference)
//
#include <hip/hip_runtime.h>
#include <hip/hip_bf16.h>
#include <cstdint>
#include <cstddef>

// JacobiKANLinear: DEGREE=5, A=B=1.0. Inputs fp32, output fp32 (HW-verified r1/r2/r5).
#define BATCH   8192
#define IN_F    1024
#define OUT_F   1024
#define KAUG    (6 * 1024)   // slab 0 = silu(x); slab j (1..5) = P_j(tanh x); P0 folded into bias

typedef __bf16 bf16x8 __attribute__((ext_vector_type(8)));
typedef float  f32x4  __attribute__((ext_vector_type(4)));

// Workspace layout (bytes), ~113.3 MB (proven available r5-r7):
static constexpr size_t WAUG_B    = (size_t)OUT_F * KAUG * 2;        // 12,582,912
static constexpr size_t BIAS2_OFF = WAUG_B;                          // 4 KB f32
static constexpr size_t AAUG_OFF  = WAUG_B + 4096;
static constexpr size_t AAUG_B    = (size_t)BATCH * KAUG * 2;        // 100,663,296
static constexpr size_t MMAP_OFF  = AAUG_OFF + AAUG_B;
static constexpr size_t NMAP_OFF  = MMAP_OFF + 1024;

// Jacobi recurrence for A=B=1 (beta_n = 0): P_k = (a_k t)P_{k-1} - (b_k)P_{k-2}
__device__ __constant__ float JAC_A[4] = {64.f/120.f, 180.f/336.f, 384.f/720.f, 700.f/1320.f};
__device__ __constant__ float JAC_B[4] = {48.f/120.f, 144.f/336.f, 320.f/720.f, 600.f/1320.f};

__device__ __forceinline__ unsigned short f2bf(float f)
{
    __hip_bfloat16 h = __float2bfloat16(f);
    return *(unsigned short*)&h;
}
__device__ __forceinline__ unsigned pack2(float lo, float hi)
{
    return (unsigned)f2bf(lo) | ((unsigned)f2bf(hi) << 16);
}
__device__ __forceinline__ float fast_tanh(float x)
{
    const float xc = fminf(fmaxf(x, -15.f), 15.f);
    const float e  = __expf(2.f * xc);
    return (e - 1.f) / (e + 1.f);
}

// ---------------- MFMA C/D layout probe (feeds epilogue) ----------------
__global__ void probe_layout(int* __restrict__ mmap, int* __restrict__ nmap)
{
    __shared__ __align__(16) __hip_bfloat16 A1[16 * 32], B1[16 * 32];
    __shared__ __align__(16) __hip_bfloat16 A2[16 * 32], B2[16 * 32];
    const int lane = threadIdx.x;
    for (int e = lane; e < 512; e += 64) {
        const int m = e >> 5, k = e & 31;
        A1[e] = __float2bfloat16((k == 0) ? (float)(m + 1) : 0.f);
        B1[e] = __float2bfloat16((k == 0) ? 1.f : 0.f);
        A2[e] = __float2bfloat16((k == 0) ? 1.f : 0.f);
        B2[e] = __float2bfloat16((k == 0) ? (float)(m + 1) : 0.f);
    }
    __syncthreads();
    const int quad = lane >> 4, mr = lane & 15;
    const int fi = mr * 4 + quad;
    f32x4 z = {};
    f32x4 d1 = __builtin_amdgcn_mfma_f32_16x16x32_bf16(((const bf16x8*)A1)[fi], ((const bf16x8*)B1)[fi], z, 0, 0, 0);
    f32x4 d2 = __builtin_amdgcn_mfma_f32_16x16x32_bf16(((const bf16x8*)A2)[fi], ((const bf16x8*)B2)[fi], z, 0, 0, 0);
#pragma unroll
    for (int r = 0; r < 4; ++r) {
        mmap[lane * 4 + r] = (int)(d1[r] + 0.5f) - 1;
        nmap[lane * 4 + r] = (int)(d2[r] + 0.5f) - 1;
    }
}

// ---------------- fused weights + bias prep ----------------
__global__ void prep_wb(const float* __restrict__ W,
                        const float* __restrict__ C,
                        const float* __restrict__ bias,
                        __hip_bfloat16* __restrict__ Waug,
                        float* __restrict__ bias2)
{
    const int o   = blockIdx.x;
    const int tid = threadIdx.x;
    const int i   = tid * 4;
    const size_t wbase = (size_t)o * KAUG;

    const float4 wv = *(const float4*)(W + (size_t)o * IN_F + i);
    ((uint2*)&Waug[wbase + i])[0] = make_uint2(pack2(wv.x, wv.y), pack2(wv.z, wv.w));

    float f[24];
    const float2* cp = (const float2*)(C + ((size_t)o * IN_F + i) * 6);
#pragma unroll
    for (int q = 0; q < 12; ++q) { const float2 v = cp[q]; f[q * 2] = v.x; f[q * 2 + 1] = v.y; }

#pragma unroll
    for (int j = 1; j <= 5; ++j) {
        ((uint2*)&Waug[wbase + (size_t)j * IN_F + i])[0] =
            make_uint2(pack2(f[0 + j], f[6 + j]), pack2(f[12 + j], f[18 + j]));
    }

    float s = f[0] + f[6] + f[12] + f[18];        // j = 0 terms
#pragma unroll
    for (int off = 32; off > 0; off >>= 1) s += __shfl_down(s, off, 64);
    __shared__ float red[4];
    if ((tid & 63) == 0) red[tid >> 6] = s;
    __syncthreads();
    if (tid == 0) bias2[o] = bias[o] + red[0] + red[1] + red[2] + red[3];
}

// ---------------- activation prep: 8 elems/thread, 16B stores ----------------
__global__ void prep_acts(const float* __restrict__ X,
                          __hip_bfloat16* __restrict__ Aaug)
{
    const int gid = blockIdx.x * 256 + threadIdx.x;
    const int b   = gid >> 7;
    const int i8  = (gid & 127) * 8;
    const float4 x0 = *(const float4*)(X + (size_t)b * IN_F + i8);
    const float4 x1 = *(const float4*)(X + (size_t)b * IN_F + i8 + 4);
    const float sx[8] = {x0.x, x0.y, x0.z, x0.w, x1.x, x1.y, x1.z, x1.w};
    const size_t base = (size_t)b * KAUG + i8;

    float sil[8], t[8], pm1[8], pm2[8];
#pragma unroll
    for (int e = 0; e < 8; ++e) {
        sil[e] = sx[e] / (1.f + __expf(-sx[e]));
        t[e]   = fast_tanh(sx[e]);
        pm2[e] = 1.f; pm1[e] = 2.f * t[e];
    }
    *(uint4*)&Aaug[base] = make_uint4(pack2(sil[0], sil[1]), pack2(sil[2], sil[3]),
                                      pack2(sil[4], sil[5]), pack2(sil[6], sil[7]));
    *(uint4*)&Aaug[base + IN_F] = make_uint4(pack2(pm1[0], pm1[1]), pack2(pm1[2], pm1[3]),
                                             pack2(pm1[4], pm1[5]), pack2(pm1[6], pm1[7]));
#pragma unroll
    for (int k = 2; k <= 5; ++k) {
#pragma unroll
        for (int e = 0; e < 8; ++e) {
            const float pk = JAC_A[k - 2] * t[e] * pm1[e] - JAC_B[k - 2] * pm2[e];
            pm2[e] = pm1[e]; pm1[e] = pk;
        }
        *(uint4*)&Aaug[base + (size_t)k * IN_F] =
            make_uint4(pack2(pm1[0], pm1[1]), pack2(pm1[2], pm1[3]),
                       pack2(pm1[4], pm1[5]), pack2(pm1[6], pm1[7]));
    }
}

// ---------------- bias init: out[b][o] = bias2[o] (split-K atomics add on top) ----
__global__ void bias_init(const float* __restrict__ bias2, float* __restrict__ out)
{
    const int gid = blockIdx.x * 256 + threadIdx.x;     // 0 .. BATCH*OUT_F/4-1
    const int row = gid >> 8;
    const int c4  = (gid & 255) * 4;
    const float4 bv = *(const float4*)(bias2 + c4);
    *(float4*)(out + (size_t)row * OUT_F + c4) = bv;
}

// ---------------- GEMM: 128x128 tile, split-K=2, swizzled LDS, atomic epilogue ----
// Bank-conflict fix: global_load_lds scatter is fixed (base + lane*16), so we
// swizzle the SOURCE column: chunk c loads global chunk c ^ ((srow>>1)&3).
// Frag read un-swizzles: quad ^ ((row>>1)&3); for row = 16t + mr this reduces
// to quad ^ ((mr>>1)&3) (lane-constant). Each bank group then serves exactly
// 2 lanes -> conflict-free (m136: 2-way is free).
__device__ __forceinline__ void async_load16(const void* g, void* l)
{
    __builtin_amdgcn_global_load_lds(
        (const __attribute__((address_space(1))) void*)g,
        (__attribute__((address_space(3))) void*)l,
        16, 0, 0);
}

__global__ __launch_bounds__(256, 4)
void gemm_kan(const __hip_bfloat16* __restrict__ Aaug,
              const __hip_bfloat16* __restrict__ Waug,
              const int* __restrict__ mmap,
              const int* __restrict__ nmap,
              float* __restrict__ out)
{
    __shared__ __align__(16) __hip_bfloat16 As[128 * 32], Bs[128 * 32];
    __shared__ __align__(16) __hip_bfloat16 As2[128 * 32], Bs2[128 * 32];

    const int tid  = threadIdx.x;
    const int lane = tid & 63;
    const int wave = tid >> 6;
    const int wm = wave & 1, wn = wave >> 1;
    const int mBase = blockIdx.y * 128;
    const int nBase = blockIdx.x * 128;
    const int kBase = blockIdx.z * (KAUG / 2);   // split-K=2

    // staging with source-side swizzle
    const int srow = tid >> 2;                       // 0..63
    const int chnk = tid & 3;                        // LDS chunk within row
    const int scol = (chnk ^ ((srow >> 1) & 3)) * 8; // swizzled global column
    const __hip_bfloat16* gA0 = Aaug + (size_t)(mBase + srow) * KAUG + scol;
    const __hip_bfloat16* gA1 = gA0 + (size_t)64 * KAUG;
    const __hip_bfloat16* gB0 = Waug + (size_t)(nBase + srow) * KAUG + scol;
    const __hip_bfloat16* gB1 = gB0 + (size_t)64 * KAUG;
    char* lA  = (char*)As  + wave * 1024;
    char* lB  = (char*)Bs  + wave * 1024;
    char* lA2 = (char*)As2 + wave * 1024;
    char* lB2 = (char*)Bs2 + wave * 1024;

    f32x4 acc[4][4] = {};
    const int quad = lane >> 4, mr = lane & 15;
    const int qsw  = quad ^ ((mr >> 1) & 3);         // un-swizzled frag chunk

    for (int k0 = kBase; k0 < kBase + KAUG / 2; k0 += 64) {
        async_load16(gA0 + k0, lA);
        async_load16(gA1 + k0, lA + 4096);
        async_load16(gB0 + k0, lB);
        async_load16(gB1 + k0, lB + 4096);
        async_load16(gA0 + k0 + 32, lA2);
        async_load16(gA1 + k0 + 32, lA2 + 4096);
        async_load16(gB0 + k0 + 32, lB2);
        async_load16(gB1 + k0 + 32, lB2 + 4096);
        __syncthreads();

        {
            const bf16x8* AsV = (const bf16x8*)As;
            const bf16x8* BsV = (const bf16x8*)Bs;
            bf16x8 a[4], b[4];
#pragma unroll
            for (int t = 0; t < 4; ++t) a[t] = AsV[(wm * 64 + t * 16 + mr) * 4 + qsw];
#pragma unroll
            for (int t = 0; t < 4; ++t) b[t] = BsV[(wn * 64 + t * 16 + mr) * 4 + qsw];
#pragma unroll
            for (int i = 0; i < 4; ++i)
#pragma unroll
                for (int jj = 0; jj < 4; ++jj)
                    acc[i][jj] = __builtin_amdgcn_mfma_f32_16x16x32_bf16(a[i], b[jj], acc[i][jj], 0, 0, 0);
        }
        {
            const bf16x8* AsV = (const bf16x8*)As2;
            const bf16x8* BsV = (const bf16x8*)Bs2;
            bf16x8 a[4], b[4];
#pragma unroll
            for (int t = 0; t < 4; ++t) a[t] = AsV[(wm * 64 + t * 16 + mr) * 4 + qsw];
#pragma unroll
            for (int t = 0; t < 4; ++t) b[t] = BsV[(wn * 64 + t * 16 + mr) * 4 + qsw];
#pragma unroll
            for (int i = 0; i < 4; ++i)
#pragma unroll
                for (int jj = 0; jj < 4; ++jj)
                    acc[i][jj] = __builtin_amdgcn_mfma_f32_16x16x32_bf16(a[i], b[jj], acc[i][jj], 0, 0, 0);
        }
        __syncthreads();
    }

    // Atomic epilogue onto bias-initialized output (split-K partial add)
    const int4 mv = ((const int4*)mmap)[lane];
    const int4 nv = ((const int4*)nmap)[lane];
    const int mm[4] = {mv.x, mv.y, mv.z, mv.w};
    const int nn[4] = {nv.x, nv.y, nv.z, nv.w};
#pragma unroll
    for (int i = 0; i < 4; ++i) {
#pragma unroll
        for (int jj = 0; jj < 4; ++jj) {
#pragma unroll
            for (int r = 0; r < 4; ++r) {
                const int row = mBase + wm * 64 + i * 16 + mm[r];
                const int col = nBase + wn * 64 + jj * 16 + nn[r];
                atomicAdd(&out[(size_t)row * OUT_F + col], acc[i][jj][r]);
            }
        }
    }
}

// ---------------- launch ----------------

extern "C" void kernel_launch(void* const* d_in, const int* in_sizes, int n_in,
                              void* d_out, int out_size, void* d_ws, size_t ws_size,
                              hipStream_t stream)
{
    (void)out_size; (void)ws_size;
    const float* x    = (const float*)d_in[0];
    const float* W    = (const float*)d_in[1];
    const float* C    = (const float*)d_in[2];
    const float* bias = (const float*)d_in[3];
    for (int i = 0; i < n_in; ++i) {
        if      (in_sizes[i] == BATCH * IN_F)     x    = (const float*)d_in[i];
        else if (in_sizes[i] == OUT_F * IN_F)     W    = (const float*)d_in[i];
        else if (in_sizes[i] == OUT_F * IN_F * 6) C    = (const float*)d_in[i];
        else if (in_sizes[i] == OUT_F)            bias = (const float*)d_in[i];
    }
    float* out = (float*)d_out;
    char* ws = (char*)d_ws;
    __hip_bfloat16* Waug  = (__hip_bfloat16*)ws;
    float*          bias2 = (float*)(ws + BIAS2_OFF);
    __hip_bfloat16* Aaug  = (__hip_bfloat16*)(ws + AAUG_OFF);
    int*            mmap  = (int*)(ws + MMAP_OFF);
    int*            nmap  = (int*)(ws + NMAP_OFF);

    probe_layout<<<dim3(1),     dim3(64),  0, stream>>>(mmap, nmap);
    prep_wb     <<<dim3(OUT_F), dim3(256), 0, stream>>>(W, C, bias, Waug, bias2);
    prep_acts   <<<dim3((BATCH * IN_F) / 2048), dim3(256), 0, stream>>>(x, Aaug);
    bias_init   <<<dim3((BATCH * OUT_F) / 1024), dim3(256), 0, stream>>>(bias2, out);
    gemm_kan    <<<dim3(OUT_F / 128, BATCH / 128, 2), dim3(256), 0, stream>>>(
        Aaug, Waug, mmap, nmap, out);
}

// Round 9
// 227.291 us; speedup vs baseline: 1.2699x; 1.2699x over previous
//
#include <hip/hip_runtime.h>
#include <hip/hip_bf16.h>
#include <cstdint>
#include <cstddef>

// JacobiKANLinear: DEGREE=5, A=B=1.0. Inputs fp32, output fp32 (HW-verified r1/r2/r5).
#define BATCH   8192
#define IN_F    1024
#define OUT_F   1024
#define KAUG    (6 * 1024)   // slab 0 = silu(x); slab j (1..5) = P_j(tanh x); P0 folded into bias

typedef __bf16 bf16x8 __attribute__((ext_vector_type(8)));
typedef float  f32x4  __attribute__((ext_vector_type(4)));

// Workspace layout (bytes), ~113.3 MB (proven available r5-r8):
static constexpr size_t WAUG_B    = (size_t)OUT_F * KAUG * 2;        // 12,582,912
static constexpr size_t BIAS2_OFF = WAUG_B;                          // 4 KB f32
static constexpr size_t AAUG_OFF  = WAUG_B + 4096;
static constexpr size_t AAUG_B    = (size_t)BATCH * KAUG * 2;        // 100,663,296
static constexpr size_t MMAP_OFF  = AAUG_OFF + AAUG_B;
static constexpr size_t NMAP_OFF  = MMAP_OFF + 1024;

// Jacobi recurrence for A=B=1 (beta_n = 0): P_k = (a_k t)P_{k-1} - (b_k)P_{k-2}
__device__ __constant__ float JAC_A[4] = {64.f/120.f, 180.f/336.f, 384.f/720.f, 700.f/1320.f};
__device__ __constant__ float JAC_B[4] = {48.f/120.f, 144.f/336.f, 320.f/720.f, 600.f/1320.f};

__device__ __forceinline__ unsigned short f2bf(float f)
{
    __hip_bfloat16 h = __float2bfloat16(f);
    return *(unsigned short*)&h;
}
__device__ __forceinline__ unsigned pack2(float lo, float hi)
{
    return (unsigned)f2bf(lo) | ((unsigned)f2bf(hi) << 16);
}
__device__ __forceinline__ float fast_tanh(float x)
{
    const float xc = fminf(fmaxf(x, -15.f), 15.f);
    const float e  = __expf(2.f * xc);
    return (e - 1.f) / (e + 1.f);
}

// ---------------- MFMA C/D layout probe (feeds epilogue) ----------------
__global__ void probe_layout(int* __restrict__ mmap, int* __restrict__ nmap)
{
    __shared__ __align__(16) __hip_bfloat16 A1[16 * 32], B1[16 * 32];
    __shared__ __align__(16) __hip_bfloat16 A2[16 * 32], B2[16 * 32];
    const int lane = threadIdx.x;
    for (int e = lane; e < 512; e += 64) {
        const int m = e >> 5, k = e & 31;
        A1[e] = __float2bfloat16((k == 0) ? (float)(m + 1) : 0.f);
        B1[e] = __float2bfloat16((k == 0) ? 1.f : 0.f);
        A2[e] = __float2bfloat16((k == 0) ? 1.f : 0.f);
        B2[e] = __float2bfloat16((k == 0) ? (float)(m + 1) : 0.f);
    }
    __syncthreads();
    const int quad = lane >> 4, mr = lane & 15;
    const int fi = mr * 4 + quad;
    f32x4 z = {};
    f32x4 d1 = __builtin_amdgcn_mfma_f32_16x16x32_bf16(((const bf16x8*)A1)[fi], ((const bf16x8*)B1)[fi], z, 0, 0, 0);
    f32x4 d2 = __builtin_amdgcn_mfma_f32_16x16x32_bf16(((const bf16x8*)A2)[fi], ((const bf16x8*)B2)[fi], z, 0, 0, 0);
#pragma unroll
    for (int r = 0; r < 4; ++r) {
        mmap[lane * 4 + r] = (int)(d1[r] + 0.5f) - 1;
        nmap[lane * 4 + r] = (int)(d2[r] + 0.5f) - 1;
    }
}

// ---------------- fused prep: blocks [0,1024) = weights+bias; [1024,5120) = acts ----
__global__ void prep_all(const float* __restrict__ X,
                         const float* __restrict__ W,
                         const float* __restrict__ C,
                         const float* __restrict__ bias,
                         __hip_bfloat16* __restrict__ Aaug,
                         __hip_bfloat16* __restrict__ Waug,
                         float* __restrict__ bias2)
{
    const int bid = blockIdx.x;
    const int tid = threadIdx.x;
    if (bid < OUT_F) {
        // --- weights + bias fold for output row o ---
        const int o = bid;
        const int i = tid * 4;
        const size_t wbase = (size_t)o * KAUG;

        const float4 wv = *(const float4*)(W + (size_t)o * IN_F + i);
        ((uint2*)&Waug[wbase + i])[0] = make_uint2(pack2(wv.x, wv.y), pack2(wv.z, wv.w));

        float f[24];   // 24 consecutive floats = C[o][i..i+3][0..5]
        const float2* cp = (const float2*)(C + ((size_t)o * IN_F + i) * 6);
#pragma unroll
        for (int q = 0; q < 12; ++q) { const float2 v = cp[q]; f[q * 2] = v.x; f[q * 2 + 1] = v.y; }
#pragma unroll
        for (int j = 1; j <= 5; ++j) {
            ((uint2*)&Waug[wbase + (size_t)j * IN_F + i])[0] =
                make_uint2(pack2(f[0 + j], f[6 + j]), pack2(f[12 + j], f[18 + j]));
        }
        float s = f[0] + f[6] + f[12] + f[18];        // j=0 terms
#pragma unroll
        for (int off = 32; off > 0; off >>= 1) s += __shfl_down(s, off, 64);
        __shared__ float red[4];
        if ((tid & 63) == 0) red[tid >> 6] = s;
        __syncthreads();
        if (tid == 0) bias2[o] = bias[o] + red[0] + red[1] + red[2] + red[3];
    } else {
        // --- activations: 8 elems/thread, 16B stores ---
        const int gid = (bid - OUT_F) * 256 + tid;
        const int b   = gid >> 7;
        const int i8  = (gid & 127) * 8;
        const float4 x0 = *(const float4*)(X + (size_t)b * IN_F + i8);
        const float4 x1 = *(const float4*)(X + (size_t)b * IN_F + i8 + 4);
        const float sx[8] = {x0.x, x0.y, x0.z, x0.w, x1.x, x1.y, x1.z, x1.w};
        const size_t base = (size_t)b * KAUG + i8;

        float sil[8], t[8], pm1[8], pm2[8];
#pragma unroll
        for (int e = 0; e < 8; ++e) {
            sil[e] = sx[e] / (1.f + __expf(-sx[e]));
            t[e]   = fast_tanh(sx[e]);
            pm2[e] = 1.f; pm1[e] = 2.f * t[e];
        }
        *(uint4*)&Aaug[base] = make_uint4(pack2(sil[0], sil[1]), pack2(sil[2], sil[3]),
                                          pack2(sil[4], sil[5]), pack2(sil[6], sil[7]));
        *(uint4*)&Aaug[base + IN_F] = make_uint4(pack2(pm1[0], pm1[1]), pack2(pm1[2], pm1[3]),
                                                 pack2(pm1[4], pm1[5]), pack2(pm1[6], pm1[7]));
#pragma unroll
        for (int k = 2; k <= 5; ++k) {
#pragma unroll
            for (int e = 0; e < 8; ++e) {
                const float pk = JAC_A[k - 2] * t[e] * pm1[e] - JAC_B[k - 2] * pm2[e];
                pm2[e] = pm1[e]; pm1[e] = pk;
            }
            *(uint4*)&Aaug[base + (size_t)k * IN_F] =
                make_uint4(pack2(pm1[0], pm1[1]), pack2(pm1[2], pm1[3]),
                           pack2(pm1[4], pm1[5]), pack2(pm1[6], pm1[7]));
        }
    }
}

// ---------------- GEMM ----------------
// 128x128 tile, BK=64 per iter, DOUBLE-BUFFERED (one barrier per iter; prefetch
// issued before compute so the barrier drain waits on loads aged by the whole
// compute phase). Grid (M-tiles=64 fastest, N-tiles=8): XCD = M-tile % 8, so
// each Aaug slab is consumed entirely within one XCD's L2 (K-window ~256 KB).
// Source-side XOR swizzle keeps ds_read_b128 conflict-free (r8: conflicts=0).
__device__ __forceinline__ void async_load16(const void* g, void* l)
{
    __builtin_amdgcn_global_load_lds(
        (const __attribute__((address_space(1))) void*)g,
        (__attribute__((address_space(3))) void*)l,
        16, 0, 0);
}

__global__ __launch_bounds__(256, 2)
void gemm_kan(const __hip_bfloat16* __restrict__ Aaug,
              const __hip_bfloat16* __restrict__ Waug,
              const float* __restrict__ bias2,
              const int* __restrict__ mmap,
              const int* __restrict__ nmap,
              float* __restrict__ out)
{
    // 8 buffers x 8 KB = 64 KB: [dbuf][chunk] for A and B
    __shared__ __align__(16) __hip_bfloat16 As[2][128 * 32], As2[2][128 * 32];
    __shared__ __align__(16) __hip_bfloat16 Bs[2][128 * 32], Bs2[2][128 * 32];

    const int tid  = threadIdx.x;
    const int lane = tid & 63;
    const int wave = tid >> 6;
    const int wm = wave & 1, wn = wave >> 1;
    const int mBase = blockIdx.x * 128;   // M fastest -> XCD = M-tile % 8
    const int nBase = blockIdx.y * 128;

    const int srow = tid >> 2;                       // 0..63
    const int chnk = tid & 3;
    const int scol = (chnk ^ ((srow >> 1) & 3)) * 8; // swizzled source column
    const __hip_bfloat16* gA0 = Aaug + (size_t)(mBase + srow) * KAUG + scol;
    const __hip_bfloat16* gA1 = gA0 + (size_t)64 * KAUG;
    const __hip_bfloat16* gB0 = Waug + (size_t)(nBase + srow) * KAUG + scol;
    const __hip_bfloat16* gB1 = gB0 + (size_t)64 * KAUG;
    const int woff = wave * 1024;   // byte offset of this wave's 16-row group

    f32x4 acc[4][4] = {};
    const int quad = lane >> 4, mr = lane & 15;
    const int qsw  = quad ^ ((mr >> 1) & 3);         // un-swizzled frag chunk

    // prologue: fill buffer 0
    {
        async_load16(gA0, (char*)As[0] + woff);
        async_load16(gA1, (char*)As[0] + woff + 4096);
        async_load16(gB0, (char*)Bs[0] + woff);
        async_load16(gB1, (char*)Bs[0] + woff + 4096);
        async_load16(gA0 + 32, (char*)As2[0] + woff);
        async_load16(gA1 + 32, (char*)As2[0] + woff + 4096);
        async_load16(gB0 + 32, (char*)Bs2[0] + woff);
        async_load16(gB1 + 32, (char*)Bs2[0] + woff + 4096);
    }
    __syncthreads();

    for (int k0 = 0; k0 < KAUG; k0 += 64) {
        const int cur = (k0 >> 6) & 1;
        const int nxt = cur ^ 1;
        if (k0 + 64 < KAUG) {   // prefetch next BK=64 into alternate buffers
            const int kn = k0 + 64;
            async_load16(gA0 + kn, (char*)As[nxt] + woff);
            async_load16(gA1 + kn, (char*)As[nxt] + woff + 4096);
            async_load16(gB0 + kn, (char*)Bs[nxt] + woff);
            async_load16(gB1 + kn, (char*)Bs[nxt] + woff + 4096);
            async_load16(gA0 + kn + 32, (char*)As2[nxt] + woff);
            async_load16(gA1 + kn + 32, (char*)As2[nxt] + woff + 4096);
            async_load16(gB0 + kn + 32, (char*)Bs2[nxt] + woff);
            async_load16(gB1 + kn + 32, (char*)Bs2[nxt] + woff + 4096);
        }
        // compute chunk 0
        {
            const bf16x8* AsV = (const bf16x8*)As[cur];
            const bf16x8* BsV = (const bf16x8*)Bs[cur];
            bf16x8 a[4], b[4];
#pragma unroll
            for (int t = 0; t < 4; ++t) a[t] = AsV[(wm * 64 + t * 16 + mr) * 4 + qsw];
#pragma unroll
            for (int t = 0; t < 4; ++t) b[t] = BsV[(wn * 64 + t * 16 + mr) * 4 + qsw];
#pragma unroll
            for (int i = 0; i < 4; ++i)
#pragma unroll
                for (int jj = 0; jj < 4; ++jj)
                    acc[i][jj] = __builtin_amdgcn_mfma_f32_16x16x32_bf16(a[i], b[jj], acc[i][jj], 0, 0, 0);
        }
        // compute chunk 1
        {
            const bf16x8* AsV = (const bf16x8*)As2[cur];
            const bf16x8* BsV = (const bf16x8*)Bs2[cur];
            bf16x8 a[4], b[4];
#pragma unroll
            for (int t = 0; t < 4; ++t) a[t] = AsV[(wm * 64 + t * 16 + mr) * 4 + qsw];
#pragma unroll
            for (int t = 0; t < 4; ++t) b[t] = BsV[(wn * 64 + t * 16 + mr) * 4 + qsw];
#pragma unroll
            for (int i = 0; i < 4; ++i)
#pragma unroll
                for (int jj = 0; jj < 4; ++jj)
                    acc[i][jj] = __builtin_amdgcn_mfma_f32_16x16x32_bf16(a[i], b[jj], acc[i][jj], 0, 0, 0);
        }
        __syncthreads();   // drains prefetch (aged by compute) + lgkm for buffer reuse
    }

    // direct-store epilogue via measured C/D maps (no split-K, no atomics)
    const int4 mv = ((const int4*)mmap)[lane];
    const int4 nv = ((const int4*)nmap)[lane];
    const int mm[4] = {mv.x, mv.y, mv.z, mv.w};
    const int nn[4] = {nv.x, nv.y, nv.z, nv.w};
#pragma unroll
    for (int i = 0; i < 4; ++i) {
#pragma unroll
        for (int jj = 0; jj < 4; ++jj) {
#pragma unroll
            for (int r = 0; r < 4; ++r) {
                const int row = mBase + wm * 64 + i * 16 + mm[r];
                const int col = nBase + wn * 64 + jj * 16 + nn[r];
                out[(size_t)row * OUT_F + col] = acc[i][jj][r] + bias2[col];
            }
        }
    }
}

// ---------------- launch ----------------

extern "C" void kernel_launch(void* const* d_in, const int* in_sizes, int n_in,
                              void* d_out, int out_size, void* d_ws, size_t ws_size,
                              hipStream_t stream)
{
    (void)out_size; (void)ws_size;
    const float* x    = (const float*)d_in[0];
    const float* W    = (const float*)d_in[1];
    const float* C    = (const float*)d_in[2];
    const float* bias = (const float*)d_in[3];
    for (int i = 0; i < n_in; ++i) {
        if      (in_sizes[i] == BATCH * IN_F)     x    = (const float*)d_in[i];
        else if (in_sizes[i] == OUT_F * IN_F)     W    = (const float*)d_in[i];
        else if (in_sizes[i] == OUT_F * IN_F * 6) C    = (const float*)d_in[i];
        else if (in_sizes[i] == OUT_F)            bias = (const float*)d_in[i];
    }
    float* out = (float*)d_out;
    char* ws = (char*)d_ws;
    __hip_bfloat16* Waug  = (__hip_bfloat16*)ws;
    float*          bias2 = (float*)(ws + BIAS2_OFF);
    __hip_bfloat16* Aaug  = (__hip_bfloat16*)(ws + AAUG_OFF);
    int*            mmap  = (int*)(ws + MMAP_OFF);
    int*            nmap  = (int*)(ws + NMAP_OFF);

    probe_layout<<<dim3(1), dim3(64), 0, stream>>>(mmap, nmap);
    prep_all<<<dim3(OUT_F + (BATCH * IN_F) / 2048), dim3(256), 0, stream>>>(
        x, W, C, bias, Aaug, Waug, bias2);
    gemm_kan<<<dim3(BATCH / 128, OUT_F / 128), dim3(256), 0, stream>>>(
        Aaug, Waug, bias2, mmap, nmap, out);
}